// Round 13
// baseline (137.492 us; speedup 1.0000x reference)
//
#include <hip/hip_runtime.h>
#include <hip/hip_fp16.h>
#include <hip/hip_bf16.h>

#define NN 256
#define AA 1024
#define JJ 4096          // B*C
#define OUTW 1152        // A + B

typedef __attribute__((ext_vector_type(8))) short short8v;
typedef __attribute__((ext_vector_type(4))) float floatx4;

__device__ __forceinline__ unsigned f2bf(float f) {
    __hip_bfloat16 h = __float2bfloat16(f);
    return (unsigned)*(unsigned short*)&h;
}
__device__ __forceinline__ short8v as8(uint4 v) {
    union { uint4 u; short8v s; } c; c.u = v; return c.s;
}

// ---------------------------------------------------------------------------
// fused: 512 blocks x 512 thr = 2 blocks/CU (all co-resident: 1024 thr/CU,
// 24 KB LDS/block, <128 VGPR). Block bid:
//  [G] gemm tile (jx = bid&63, ny = bid>>6): rows ny*32..+32, cols jx*64..+64
//      of M = x @ T (bf16 MFMA 16x16x32, f32 acc, f16 out). r8-verified
//      geometry: TK=64, 16 chunks, dist-2 register prefetch, double LDS buf,
//      one barrier pair per chunk, XOR swizzle byte^=((row&7)<<4) write+read.
//      8 waves: wave w -> rows (w&1)*16..+16, cols (w>>1)*16..+16 (2 MFMA/chk).
//      Epilogue: Mh stores -> __syncthreads (drains each wave's vmcnt) ->
//      tid0: __threadfence + device atomicAdd(flag[jx]) (r7-validated).
//  [C] x-copy for bid<128 (2 rows each).
//  [P] pairwise for (b = bid&127, q = bid>>7): spin flag[b>>1]==8 (only 8
//      producers -- partial wait, not r7's global convoy), __threadfence,
//      stage M[:,b,:] into 80B-padded LDS rows, r8-verified body:
//      thread = 2n x 16m, rv reads wave-uniform 2-addr broadcast (free).
// ---------------------------------------------------------------------------
__global__ __launch_bounds__(512) void fused(const float* __restrict__ x,
                                             const float* __restrict__ T,
                                             float* __restrict__ out,
                                             __half* __restrict__ Mh,
                                             unsigned* __restrict__ flags) {
    __shared__ __align__(16) char arena[24576];
    // gemm: A bufs @0,4096 (4KB each); B bufs @8192,16384 (8KB each)
    // pairwise: Mb @0 (256 rows x 80B = 20KB); red @20480 (16x64 f32 = 4KB)

    const int bid = blockIdx.x;
    const int tid = threadIdx.x;
    const int lane = tid & 63;
    const int w = tid >> 6;                   // 0..7

    // ================= phase G: gemm tile =================
    const int jx = bid & 63;
    const int ny = bid >> 6;
    const int col0 = jx * 64;
    const int row0 = ny * 32;

    // A staging: 512 thr x 1 float4 -> uint2 (32 rows x 64 k)
    const int xr = tid >> 4;                  // 0..31
    const int xk4 = (tid & 15) * 4;           // 0..60
    const float* xp = x + (size_t)(row0 + xr) * AA + xk4;
    const int xW = xr * 128 + ((xk4 * 2) ^ ((xr & 7) << 4));

    // B staging: 512 thr x 8 strided f32 -> uint4 (64 cols x 64 k)
    const int pc = tid & 63;                  // col
    const int kq = tid >> 6;                  // 0..7 (8 k each)
    const float* tp = T + (size_t)(kq * 8) * JJ + col0 + pc;
    const int tW = pc * 128 + ((kq * 16) ^ ((pc & 7) << 4));

    // compute: wave w -> rows rh..rh+16, cols cq..cq+16
    const int rf = lane & 15;
    const int g = lane >> 4;
    const int rh = (w & 1) * 16;
    const int cq = (w >> 1) * 16;
    const int fsw = (rf & 7) << 4;
    const int aRow = (rh + rf) * 128;
    const int bRow = (cq + rf) * 128;
    const int k0 = (g * 16) ^ fsw;
    const int k1 = (64 + g * 16) ^ fsw;

    floatx4 acc = {0.f, 0.f, 0.f, 0.f};

    struct Pref { float4 xa; float t0, t1, t2, t3, t4, t5, t6, t7; };
    Pref PA, PB;
    auto LOAD = [&](Pref& S, int C) {
        S.xa = *(const float4*)(xp + C * 64);
        const float* q = tp + (size_t)C * 64 * JJ;
        S.t0 = q[0];      S.t1 = q[JJ];     S.t2 = q[2 * JJ]; S.t3 = q[3 * JJ];
        S.t4 = q[4 * JJ]; S.t5 = q[5 * JJ]; S.t6 = q[6 * JJ]; S.t7 = q[7 * JJ];
    };
    auto STAGE = [&](const Pref& S, int aOff, int bOff) {
        uint2 pa;
        pa.x = f2bf(S.xa.x) | (f2bf(S.xa.y) << 16);
        pa.y = f2bf(S.xa.z) | (f2bf(S.xa.w) << 16);
        *(uint2*)(arena + aOff + xW) = pa;
        uint4 pb;
        pb.x = f2bf(S.t0) | (f2bf(S.t1) << 16);
        pb.y = f2bf(S.t2) | (f2bf(S.t3) << 16);
        pb.z = f2bf(S.t4) | (f2bf(S.t5) << 16);
        pb.w = f2bf(S.t6) | (f2bf(S.t7) << 16);
        *(uint4*)(arena + bOff + tW) = pb;
    };
    auto COMP = [&](int aOff, int bOff) {
        short8v a0 = *(const short8v*)(arena + aOff + aRow + k0);
        short8v b0 = *(const short8v*)(arena + bOff + bRow + k0);
        acc = __builtin_amdgcn_mfma_f32_16x16x32_bf16(a0, b0, acc, 0, 0, 0);
        short8v a1 = *(const short8v*)(arena + aOff + aRow + k1);
        short8v b1 = *(const short8v*)(arena + bOff + bRow + k1);
        acc = __builtin_amdgcn_mfma_f32_16x16x32_bf16(a1, b1, acc, 0, 0, 0);
    };

    LOAD(PA, 0);
    LOAD(PB, 1);

#pragma unroll 1
    for (int c = 0; c < 16; c += 2) {
        __builtin_amdgcn_s_barrier();
        STAGE(PA, 0, 8192);
        if (c + 2 < 16) LOAD(PA, c + 2);
        asm volatile("s_waitcnt lgkmcnt(0)" ::: "memory");
        __builtin_amdgcn_sched_barrier(0);
        __builtin_amdgcn_s_barrier();
        COMP(0, 8192);

        __builtin_amdgcn_s_barrier();
        STAGE(PB, 4096, 16384);
        if (c + 3 < 16) LOAD(PB, c + 3);
        asm volatile("s_waitcnt lgkmcnt(0)" ::: "memory");
        __builtin_amdgcn_sched_barrier(0);
        __builtin_amdgcn_s_barrier();
        COMP(4096, 16384);
    }

    // epilogue: C/D layout col = lane&15, row = (lane>>4)*4 + reg
    {
        const int colw = col0 + cq + rf;
        const int rbase = row0 + rh + g * 4;
#pragma unroll
        for (int r = 0; r < 4; ++r)
            Mh[(size_t)(rbase + r) * JJ + colw] = __float2half(acc[r]);
    }
    __syncthreads();                          // per-wave vmcnt drained here
    if (tid == 0) {
        __threadfence();                      // release: L2 writeback
        atomicAdd(&flags[jx], 1u);            // device-scope (m20)
    }

    // ================= phase C: x-copy =================
    const int b = bid & 127;
    const int q = bid >> 7;
    if (bid < 128) {
        const int row = bid * 2 + (tid >> 8);
        const int c4 = (tid & 255) * 4;
        *(float4*)&out[(size_t)row * OUTW + c4] =
            *(const float4*)&x[(size_t)row * AA + c4];
    }

    // ================= phase P: pairwise =================
    if (tid == 0) {
        while (__hip_atomic_load(&flags[b >> 1], __ATOMIC_RELAXED,
                                 __HIP_MEMORY_SCOPE_AGENT) < 8u) {
            __builtin_amdgcn_s_sleep(2);
        }
    }
    __syncthreads();
    __threadfence();                          // acquire: invalidate L1/L2

    char* Mb = arena;                         // 256 rows x 80 B (pad: 4-way max)
    float (*red)[64] = (float(*)[64])(arena + 20480);

    {   // stage M[:, b, :]: 2 thr/row, 32B each
        const int m = tid >> 1;
        const int ch = (tid & 1) * 32;        // byte offset in row
        const __half* src = &Mh[(size_t)m * JJ + b * 32 + (tid & 1) * 16];
        uint4 v0 = *(const uint4*)(src);
        uint4 v1 = *(const uint4*)(src + 8);
        *(uint4*)(Mb + m * 80 + ch) = v0;
        *(uint4*)(Mb + m * 80 + ch + 16) = v1;
    }

    const int np = (tid & 31) * 2;
    const int mg = tid >> 5;                  // 0..15, wave spans 2 (free bcast)
    const int n0 = q * 64 + np;

    union u4h { uint4 u; __half2 hh[4]; };
    u4h mv[2][4];
    __syncthreads();
#pragma unroll
    for (int r = 0; r < 2; ++r)
#pragma unroll
        for (int i = 0; i < 4; ++i)
            mv[r][i].u = *(const uint4*)(Mb + (n0 + r) * 80 + i * 16);

    float o0 = 0.f, o1 = 0.f;
    const int m0 = mg * 16;
#pragma unroll 4
    for (int m = m0; m < m0 + 16; ++m) {
        u4h rv[4];
#pragma unroll
        for (int i = 0; i < 4; ++i)
            rv[i].u = *(const uint4*)(Mb + m * 80 + i * 16);
#pragma unroll
        for (int r = 0; r < 2; ++r) {
            __half2 a0 = __habs2(__hsub2(mv[r][0].hh[0], rv[0].hh[0]));
            __half2 a1 = __habs2(__hsub2(mv[r][0].hh[1], rv[0].hh[1]));
            __half2 a2 = __habs2(__hsub2(mv[r][0].hh[2], rv[0].hh[2]));
            __half2 a3 = __habs2(__hsub2(mv[r][0].hh[3], rv[0].hh[3]));
#pragma unroll
            for (int i = 1; i < 4; ++i) {
                a0 = __hadd2(a0, __habs2(__hsub2(mv[r][i].hh[0], rv[i].hh[0])));
                a1 = __hadd2(a1, __habs2(__hsub2(mv[r][i].hh[1], rv[i].hh[1])));
                a2 = __hadd2(a2, __habs2(__hsub2(mv[r][i].hh[2], rv[i].hh[2])));
                a3 = __hadd2(a3, __habs2(__hsub2(mv[r][i].hh[3], rv[i].hh[3])));
            }
            __half2 s = __hadd2(__hadd2(a0, a1), __hadd2(a2, a3));
            float2 lf = __half22float2(s);
            float e = __expf(-(lf.x + lf.y));
            if (r == 0) o0 += e; else o1 += e;
        }
    }

    *(float2*)&red[mg][np] = make_float2(o0, o1);
    __syncthreads();
    if (tid < 64) {
        float s = 0.f;
#pragma unroll
        for (int g2 = 0; g2 < 16; ++g2) s += red[g2][tid];
        out[(size_t)(q * 64 + tid) * OUTW + AA + b] = s;
    }
}

// ===========================================================================
extern "C" void kernel_launch(void* const* d_in, const int* in_sizes, int n_in,
                              void* d_out, int out_size, void* d_ws, size_t ws_size,
                              hipStream_t stream) {
    const float* x = (const float*)d_in[0];
    const float* T = (const float*)d_in[1];
    float* out = (float*)d_out;
    __half* Mh = (__half*)d_ws;                               // 2 MB
    unsigned* flags = (unsigned*)((char*)d_ws + (size_t)NN * JJ * 2);

    hipMemsetAsync(flags, 0, 64 * sizeof(unsigned), stream);  // capture-safe
    fused<<<512, 512, 0, stream>>>(x, T, out, Mh, flags);
}

// Round 14
// 34.053 us; speedup vs baseline: 4.0375x; 4.0375x over previous
//
#include <hip/hip_runtime.h>
#include <hip/hip_fp16.h>
#include <hip/hip_bf16.h>

#define NN 256
#define AA 1024
#define JJ 4096          // B*C
#define OUTW 1152        // A + B

typedef __attribute__((ext_vector_type(8))) short short8v;
typedef __attribute__((ext_vector_type(4))) float floatx4;

__device__ __forceinline__ unsigned f2bf(float f) {
    __hip_bfloat16 h = __float2bfloat16(f);
    return (unsigned)*(unsigned short*)&h;
}

// ---------------------------------------------------------------------------
// gemm: M[n][j] = sum_k x[n][k]*T[k][j]; f32 in, bf16 MFMA 16x16x32, f16 out.
// r8-verified structure with TK 64 -> 128: 8 chunks instead of 16 -> half the
// barrier intervals, 2x MFMA per interval (8/wave), same total stage work.
// Tile 32n x 64j. Grid (64 j, 8 n) = 512 blocks (2/CU), 256 thr (4 waves).
// Schedule per chunk (r8-exact): STAGE(c) ; LOAD(c+2)->regs ; __syncthreads ;
// COMP(c) -- so COMP(c) and STAGE(c+1) share one barrier interval (overlap),
// and STAGE(c+2) is separated from COMP(c) by a barrier (race-free).
// LDS [row][128k] bf16 (256B rows), XOR swizzle byte ^= ((row&7)<<4) on write
// AND read (rule 21; swizzle bits 4-6, k-offsets bits 4-7 -> stays in-row).
// Blocks sharing a T j-slice are bid%64-congruent -> same XCD L2.
// ---------------------------------------------------------------------------
__global__ __launch_bounds__(256) void gemm(const float* __restrict__ x,
                                            const float* __restrict__ T,
                                            __half* __restrict__ Mh) {
    __shared__ unsigned short xs[2][32 * 128];   // 8 KB each
    __shared__ unsigned short ts[2][64 * 128];   // 16 KB each

    const int tid = threadIdx.x;
    const int lane = tid & 63;
    const int w = tid >> 6;
    const int col0 = blockIdx.x * 64;
    const int row0 = blockIdx.y * 32;

    // A staging: 1 row x 16 k per thread
    const int xr = tid >> 3;                  // 0..31
    const int xk = (tid & 7) * 16;            // 0..112
    const float* xp = x + (size_t)(row0 + xr) * AA + xk;
    const int xsw = (xr & 7) << 4;
    const int xW0 = xr * 256 + ((xk * 2) ^ xsw);
    const int xW1 = xr * 256 + ((xk * 2 + 16) ^ xsw);

    // B staging: 4 j x 8 k per thread (transpose + convert)
    const int tj = (tid & 15) * 4;
    const int kr8 = (tid >> 4) * 8;           // 0..120
    const float* tp = T + (size_t)kr8 * JJ + col0 + tj;
    int tWr[4];
#pragma unroll
    for (int q = 0; q < 4; ++q) {
        const int row = tj + q;
        tWr[q] = row * 256 + ((kr8 * 2) ^ ((row & 7) << 4));
    }

    // compute assignments: wave w -> rows (w&1)*16..+16, cols (w>>1)*32..+32
    const int rf = lane & 15;
    const int g = lane >> 4;
    const int nh = w & 1;
    const int jh = w >> 1;
    const int fsw = (rf & 7) << 4;
    const int aBase = (nh * 16 + rf) * 256;
    const int b0Base = (jh * 32 + rf) * 256;
    const int b1Base = (jh * 32 + 16 + rf) * 256;
    int kOff[4];
#pragma unroll
    for (int ks = 0; ks < 4; ++ks) kOff[ks] = (ks * 64 + g * 16) ^ fsw;

    floatx4 acc0 = {0.f, 0.f, 0.f, 0.f};
    floatx4 acc1 = {0.f, 0.f, 0.f, 0.f};

    struct Pref { float4 xa0, xa1, xa2, xa3, t0, t1, t2, t3, t4, t5, t6, t7; };
    Pref PA, PB;
    auto LOAD = [&](Pref& S, int C) {
        const float* xq = xp + C * 128;
        S.xa0 = *(const float4*)(xq);
        S.xa1 = *(const float4*)(xq + 4);
        S.xa2 = *(const float4*)(xq + 8);
        S.xa3 = *(const float4*)(xq + 12);
        const float* tq = tp + (size_t)C * 128 * JJ;
        S.t0 = *(const float4*)(tq);
        S.t1 = *(const float4*)(tq + JJ);
        S.t2 = *(const float4*)(tq + 2 * JJ);
        S.t3 = *(const float4*)(tq + 3 * JJ);
        S.t4 = *(const float4*)(tq + 4 * JJ);
        S.t5 = *(const float4*)(tq + 5 * JJ);
        S.t6 = *(const float4*)(tq + 6 * JJ);
        S.t7 = *(const float4*)(tq + 7 * JJ);
    };
    auto STAGE = [&](const Pref& S, int buf) {
        uint4 pa;
        pa.x = f2bf(S.xa0.x) | (f2bf(S.xa0.y) << 16);
        pa.y = f2bf(S.xa0.z) | (f2bf(S.xa0.w) << 16);
        pa.z = f2bf(S.xa1.x) | (f2bf(S.xa1.y) << 16);
        pa.w = f2bf(S.xa1.z) | (f2bf(S.xa1.w) << 16);
        *(uint4*)((char*)xs[buf] + xW0) = pa;
        pa.x = f2bf(S.xa2.x) | (f2bf(S.xa2.y) << 16);
        pa.y = f2bf(S.xa2.z) | (f2bf(S.xa2.w) << 16);
        pa.z = f2bf(S.xa3.x) | (f2bf(S.xa3.y) << 16);
        pa.w = f2bf(S.xa3.z) | (f2bf(S.xa3.w) << 16);
        *(uint4*)((char*)xs[buf] + xW1) = pa;
        uint4 pb;
        pb.x = f2bf(S.t0.x) | (f2bf(S.t1.x) << 16);
        pb.y = f2bf(S.t2.x) | (f2bf(S.t3.x) << 16);
        pb.z = f2bf(S.t4.x) | (f2bf(S.t5.x) << 16);
        pb.w = f2bf(S.t6.x) | (f2bf(S.t7.x) << 16);
        *(uint4*)((char*)ts[buf] + tWr[0]) = pb;
        pb.x = f2bf(S.t0.y) | (f2bf(S.t1.y) << 16);
        pb.y = f2bf(S.t2.y) | (f2bf(S.t3.y) << 16);
        pb.z = f2bf(S.t4.y) | (f2bf(S.t5.y) << 16);
        pb.w = f2bf(S.t6.y) | (f2bf(S.t7.y) << 16);
        *(uint4*)((char*)ts[buf] + tWr[1]) = pb;
        pb.x = f2bf(S.t0.z) | (f2bf(S.t1.z) << 16);
        pb.y = f2bf(S.t2.z) | (f2bf(S.t3.z) << 16);
        pb.z = f2bf(S.t4.z) | (f2bf(S.t5.z) << 16);
        pb.w = f2bf(S.t6.z) | (f2bf(S.t7.z) << 16);
        *(uint4*)((char*)ts[buf] + tWr[2]) = pb;
        pb.x = f2bf(S.t0.w) | (f2bf(S.t1.w) << 16);
        pb.y = f2bf(S.t2.w) | (f2bf(S.t3.w) << 16);
        pb.z = f2bf(S.t4.w) | (f2bf(S.t5.w) << 16);
        pb.w = f2bf(S.t6.w) | (f2bf(S.t7.w) << 16);
        *(uint4*)((char*)ts[buf] + tWr[3]) = pb;
    };
    auto COMP = [&](int buf) {
#pragma unroll
        for (int ks = 0; ks < 4; ++ks) {
            short8v a = *(const short8v*)((char*)xs[buf] + aBase + kOff[ks]);
            short8v b0 = *(const short8v*)((char*)ts[buf] + b0Base + kOff[ks]);
            short8v b1 = *(const short8v*)((char*)ts[buf] + b1Base + kOff[ks]);
            acc0 = __builtin_amdgcn_mfma_f32_16x16x32_bf16(a, b0, acc0, 0, 0, 0);
            acc1 = __builtin_amdgcn_mfma_f32_16x16x32_bf16(a, b1, acc1, 0, 0, 0);
        }
    };

    LOAD(PA, 0);
    LOAD(PB, 1);

#pragma unroll 1
    for (int c = 0; c < 8; c += 2) {
        STAGE(PA, 0);
        if (c + 2 < 8) LOAD(PA, c + 2);
        __syncthreads();
        COMP(0);                               // overlaps next STAGE across waves

        STAGE(PB, 1);
        if (c + 3 < 8) LOAD(PB, c + 3);
        __syncthreads();
        COMP(1);
    }

    // C/D layout: col = lane&15, row = (lane>>4)*4 + reg
    const int colw = col0 + jh * 32 + rf;
    const int rbase = row0 + nh * 16 + g * 4;
#pragma unroll
    for (int r = 0; r < 4; ++r) {
        Mh[(size_t)(rbase + r) * JJ + colw] = __float2half(acc0[r]);
        Mh[(size_t)(rbase + r) * JJ + colw + 16] = __float2half(acc1[r]);
    }
}

// ---------------------------------------------------------------------------
// pairwise: r8-verified EXACT. 512 blocks = (b = bid&127, q = bid>>7),
// 512 thr = 32 n-pairs x 16 m-groups (2 blocks/CU). Thread: 2 n x 16 m.
// rv reads wave-uniform 2-addr broadcast (free, m136). x-copy folded bid<128.
// ---------------------------------------------------------------------------
__global__ __launch_bounds__(512) void pairwise(const __half* __restrict__ Mh,
                                                const float* __restrict__ x,
                                                float* __restrict__ out) {
    __shared__ __half Mb[256][32];    // 16 KB
    __shared__ float red[16][64];     // 4 KB
    const int bid = blockIdx.x;
    const int b = bid & 127;
    const int q = bid >> 7;           // n-quarter 0..3
    const int tid = threadIdx.x;

    if (bid < 128) {
        const int row = bid * 2 + (tid >> 8);
        const int c4 = (tid & 255) * 4;
        *(float4*)&out[(size_t)row * OUTW + c4] =
            *(const float4*)&x[(size_t)row * AA + c4];
    }

    {   // stage all 256 rows of M[:, b, :]
        const int m = tid >> 1;
        const int ch = (tid & 1) * 16;
        *(uint4*)&Mb[m][ch] = *(const uint4*)&Mh[(size_t)m * JJ + b * 32 + ch];
        *(uint4*)&Mb[m][ch + 8] =
            *(const uint4*)&Mh[(size_t)m * JJ + b * 32 + ch + 8];
    }

    const int np = (tid & 31) * 2;    // n-pair within quarter (0..62)
    const int mg = tid >> 5;          // m-group 0..15
    const int n0 = q * 64 + np;

    union u4h { uint4 u; __half2 hh[4]; };
    u4h mv[2][4];
#pragma unroll
    for (int r = 0; r < 2; ++r)
#pragma unroll
        for (int i = 0; i < 4; ++i)
            mv[r][i].u = *(const uint4*)&Mh[(size_t)(n0 + r) * JJ + b * 32 + i * 8];

    __syncthreads();

    float o0 = 0.f, o1 = 0.f;
    const int m0 = mg * 16;
    for (int m = m0; m < m0 + 16; ++m) {
        u4h rv[4];
#pragma unroll
        for (int i = 0; i < 4; ++i) rv[i].u = *(const uint4*)&Mb[m][i * 8];
#pragma unroll
        for (int r = 0; r < 2; ++r) {
            __half2 a0 = __habs2(__hsub2(mv[r][0].hh[0], rv[0].hh[0]));
            __half2 a1 = __habs2(__hsub2(mv[r][0].hh[1], rv[0].hh[1]));
            __half2 a2 = __habs2(__hsub2(mv[r][0].hh[2], rv[0].hh[2]));
            __half2 a3 = __habs2(__hsub2(mv[r][0].hh[3], rv[0].hh[3]));
#pragma unroll
            for (int i = 1; i < 4; ++i) {
                a0 = __hadd2(a0, __habs2(__hsub2(mv[r][i].hh[0], rv[i].hh[0])));
                a1 = __hadd2(a1, __habs2(__hsub2(mv[r][i].hh[1], rv[i].hh[1])));
                a2 = __hadd2(a2, __habs2(__hsub2(mv[r][i].hh[2], rv[i].hh[2])));
                a3 = __hadd2(a3, __habs2(__hsub2(mv[r][i].hh[3], rv[i].hh[3])));
            }
            __half2 s = __hadd2(__hadd2(a0, a1), __hadd2(a2, a3));
            float2 lf = __half22float2(s);
            float e = __expf(-(lf.x + lf.y));
            if (r == 0) o0 += e; else o1 += e;
        }
    }

    *(float2*)&red[mg][np] = make_float2(o0, o1);
    __syncthreads();
    if (tid < 64) {
        float s = 0.f;
#pragma unroll
        for (int g2 = 0; g2 < 16; ++g2) s += red[g2][tid];
        out[(size_t)(q * 64 + tid) * OUTW + AA + b] = s;
    }
}

// ===========================================================================
extern "C" void kernel_launch(void* const* d_in, const int* in_sizes, int n_in,
                              void* d_out, int out_size, void* d_ws, size_t ws_size,
                              hipStream_t stream) {
    const float* x = (const float*)d_in[0];
    const float* T = (const float*)d_in[1];
    float* out = (float*)d_out;
    __half* Mh = (__half*)d_ws;               // 2 MB

    gemm<<<dim3(64, 8), 256, 0, stream>>>(x, T, Mh);
    pairwise<<<512, 512, 0, stream>>>(Mh, x, out);
}